// Round 3
// baseline (3024.045 us; speedup 1.0000x reference)
//
#include <hip/hip_runtime.h>
#include <hip/hip_bf16.h>
#include <stdint.h>

// Persistent-RNN, R3: contention-free flags + lane-parallel poll + split-plane state.
//  - 256 blocks (1/CU), 256 threads (4 waves). 8 batch-groups x 32 blocks.
//  - Block (g,m): batch rows [16g,16g+16), hidden cols [32m,32m+32).
//  - W_hh/W_ih held as bf16 hi+lo MFMA B-fragments in REGISTERS for all 512 steps.
//  - R2 -> R3:
//      * counter atomicAdd (32 contended RMWs/step) -> per-block flag stores
//        (64B-strided, zero contention), lane-parallel poll with __all();
//        poll done by every wave -> post-poll __syncthreads removed.
//      * state stored as SPLIT hi/lo bf16 planes -> loads are ready-made MFMA
//        fragments, ~400cyc/step of unpack VALU removed from the load path.
//      * reorder: x loads -> poll -> state loads issued -> x split+MFMA (hides
//        state-load latency) -> state MFMAs.
//  - All inter-block data/flag traffic via relaxed agent-scope atomics
//    (sc-bit L2-bypass, IC-coherent) -- no cache-maintenance ops, no dispatch-
//    order or XCD-placement assumptions (G16-safe).

#define TSTEPS 512
#define BATCH  128
#define NI     256
#define NH     1024
#define NO     128
#define GROUPS 8
#define CPG    32
#define BG     16
#define COLS   32
#define FSTRIDE 16   // u32 stride between flags = 64B (own line each)

typedef __attribute__((ext_vector_type(8))) short s16x8;
typedef __attribute__((ext_vector_type(4))) short s16x4;
typedef __attribute__((ext_vector_type(4))) float f32x4;
typedef unsigned long long ull;

__device__ __forceinline__ unsigned short f2bf_rne(float f) {
  unsigned u = __builtin_bit_cast(unsigned, f);
  unsigned r = u + 0x7fffu + ((u >> 16) & 1u);
  return (unsigned short)(r >> 16);
}
__device__ __forceinline__ float bf2f(unsigned short h) {
  unsigned u = ((unsigned)h) << 16;
  return __builtin_bit_cast(float, u);
}
__device__ __forceinline__ void split_bf(float v, short &hi, short &lo) {
  unsigned short h = f2bf_rne(v);
  hi = (short)h;
  lo = (short)f2bf_rne(v - bf2f(h));
}
__device__ __forceinline__ f32x4 mfma16(s16x8 a, s16x8 b, f32x4 c) {
  return __builtin_amdgcn_mfma_f32_16x16x32_bf16(a, b, c, 0, 0, 0);
}
__device__ __forceinline__ float fast_tanh(float a) {
  float cl = fminf(fmaxf(a, -15.f), 15.f);
  float e  = __expf(2.f * cl);
  return (e - 1.f) / (e + 1.f);
}
__device__ __forceinline__ s16x8 cat8(ull a, ull b) {
  s16x4 x = __builtin_bit_cast(s16x4, a);
  s16x4 y = __builtin_bit_cast(s16x4, b);
  return __builtin_shufflevector(x, y, 0, 1, 2, 3, 4, 5, 6, 7);
}

__global__ __launch_bounds__(256, 1)
void rnn_persistent(const float* __restrict__ x,
                    const float* __restrict__ W_ih,
                    const float* __restrict__ W_hh,
                    const float* __restrict__ b_ih,
                    const float* __restrict__ b_hh,
                    unsigned short* __restrict__ SH,   // [2][128][1024] bf16 hi plane
                    unsigned short* __restrict__ SL,   // [2][128][1024] bf16 lo plane
                    unsigned*       __restrict__ flags)// [8][32][FSTRIDE]
{
  const int tid  = threadIdx.x;
  const int wave = tid >> 6;
  const int lane = tid & 63;
  const int lr   = lane & 15;   // row (A/m) or col (B/n) within tile
  const int lq   = lane >> 4;   // quad
  const int g    = blockIdx.x >> 5;
  const int m    = blockIdx.x & 31;
  const int row0 = g * BG;
  const int h0   = m * COLS;

  __shared__ float red[4][512];

  // ---- persistent W_hh B-fragments: wave's K-quarter, 2 n-tiles, hi/lo ----
  // B[k][n] = W_hh[h0+n][k]; lane holds k = quad*8+j, n = lane&15.
  s16x8 whh_hi[2][8], whh_lo[2][8];
  const int kq0 = wave * 256;
  #pragma unroll
  for (int nt = 0; nt < 2; ++nt) {
    const int h = h0 + nt * 16 + lr;
    #pragma unroll
    for (int kb = 0; kb < 8; ++kb) {
      const float* p = W_hh + (size_t)h * NH + kq0 + kb * 32 + lq * 8;
      s16x8 hi, lo;
      #pragma unroll
      for (int j = 0; j < 8; ++j) { short a, b; split_bf(p[j], a, b); hi[j] = a; lo[j] = b; }
      whh_hi[nt][kb] = hi; whh_lo[nt][kb] = lo;
    }
  }
  // ---- persistent W_ih B-fragments: wave's 64-wide input K-slice ----
  s16x8 wih_hi[2][2], wih_lo[2][2];
  const int iq0 = wave * 64;
  #pragma unroll
  for (int nt = 0; nt < 2; ++nt) {
    const int h = h0 + nt * 16 + lr;
    #pragma unroll
    for (int kb = 0; kb < 2; ++kb) {
      const float* p = W_ih + (size_t)h * NI + iq0 + kb * 32 + lq * 8;
      s16x8 hi, lo;
      #pragma unroll
      for (int j = 0; j < 8; ++j) { short a, b; split_bf(p[j], a, b); hi[j] = a; lo[j] = b; }
      wih_hi[nt][kb] = hi; wih_lo[nt][kb] = lo;
    }
  }

  // epilogue ownership: thread j -> row j>>4, columns 2*(j&15), 2*(j&15)+1
  const int er  = tid >> 4;
  const int ec  = (tid & 15) * 2;
  const float bias0 = b_ih[h0 + ec]     + b_hh[h0 + ec];
  const float bias1 = b_ih[h0 + ec + 1] + b_hh[h0 + ec + 1];

  unsigned* myflag   = flags + ((size_t)(g * CPG + m)) * FSTRIDE;
  const unsigned* pollflag = flags + ((size_t)(g * CPG + (lane & 31))) * FSTRIDE;

  for (int t = 0; t < TSTEPS; ++t) {
    // ---------- issue x loads (land during the poll wait) ----------
    float xv[16];
    {
      const float* xp = x + (size_t)t * BATCH * NI + (size_t)(row0 + lr) * NI + iq0 + lq * 8;
      #pragma unroll
      for (int kb = 0; kb < 2; ++kb)
        #pragma unroll
        for (int j = 0; j < 8; ++j) xv[kb * 8 + j] = xp[kb * 32 + j];
    }
    // ---------- lane-parallel poll: all 32 producer flags >= t ----------
    unsigned dep = 0;
    if (t > 0) {
      unsigned v;
      do {
        v = __hip_atomic_load(pollflag, __ATOMIC_RELAXED, __HIP_MEMORY_SCOPE_AGENT);
      } while (!__all((int)(v >= (unsigned)t)));
      dep = v >> 20;   // always 0 (flags <= 512); forces addr data-dep on polled value
    }
    // ---------- issue all state loads (IC-coherent), fragments land ready ----------
    const ull* hb = (const ull*)(SH + (size_t)(t & 1) * BATCH * NH
                                 + (size_t)(row0 + lr) * NH + kq0 + lq * 8) + dep;
    const ull* lb = (const ull*)(SL + (size_t)(t & 1) * BATCH * NH
                                 + (size_t)(row0 + lr) * NH + kq0 + lq * 8) + dep;
    ull svh[16], svl[16];
    #pragma unroll
    for (int kb = 0; kb < 8; ++kb) {
      svh[kb * 2]     = __hip_atomic_load(hb + kb * 8,     __ATOMIC_RELAXED, __HIP_MEMORY_SCOPE_AGENT);
      svh[kb * 2 + 1] = __hip_atomic_load(hb + kb * 8 + 1, __ATOMIC_RELAXED, __HIP_MEMORY_SCOPE_AGENT);
      svl[kb * 2]     = __hip_atomic_load(lb + kb * 8,     __ATOMIC_RELAXED, __HIP_MEMORY_SCOPE_AGENT);
      svl[kb * 2 + 1] = __hip_atomic_load(lb + kb * 8 + 1, __ATOMIC_RELAXED, __HIP_MEMORY_SCOPE_AGENT);
    }
    // ---------- x projection (VALU+MFMA in the state-load shadow) ----------
    f32x4 acc0 = {0.f, 0.f, 0.f, 0.f}, acc1 = {0.f, 0.f, 0.f, 0.f};
    #pragma unroll
    for (int kb = 0; kb < 2; ++kb) {
      s16x8 xhi, xlo;
      #pragma unroll
      for (int j = 0; j < 8; ++j) { short a, b; split_bf(xv[kb * 8 + j], a, b); xhi[j] = a; xlo[j] = b; }
      acc0 = mfma16(xhi, wih_hi[0][kb], acc0);
      acc0 = mfma16(xhi, wih_lo[0][kb], acc0);
      acc0 = mfma16(xlo, wih_hi[0][kb], acc0);
      acc1 = mfma16(xhi, wih_hi[1][kb], acc1);
      acc1 = mfma16(xhi, wih_lo[1][kb], acc1);
      acc1 = mfma16(xlo, wih_hi[1][kb], acc1);
    }
    // ---------- recurrent MFMAs: A = state fragments (zero unpack) ----------
    #pragma unroll
    for (int kb = 0; kb < 8; ++kb) {
      s16x8 shi = cat8(svh[kb * 2], svh[kb * 2 + 1]);
      s16x8 slo = cat8(svl[kb * 2], svl[kb * 2 + 1]);
      acc0 = mfma16(shi, whh_hi[0][kb], acc0);
      acc0 = mfma16(shi, whh_lo[0][kb], acc0);
      acc0 = mfma16(slo, whh_hi[0][kb], acc0);
      acc1 = mfma16(shi, whh_hi[1][kb], acc1);
      acc1 = mfma16(shi, whh_lo[1][kb], acc1);
      acc1 = mfma16(slo, whh_hi[1][kb], acc1);
    }
    // ---------- cross-wave K reduction in LDS ----------
    // C/D layout: col = lane&15, row = quad*4 + reg  (m89/m91 verified)
    #pragma unroll
    for (int r = 0; r < 4; ++r) {
      red[wave][(lq * 4 + r) * 32 + lr]      = acc0[r];
      red[wave][(lq * 4 + r) * 32 + 16 + lr] = acc1[r];
    }
    __syncthreads();
    {
      const int e0 = er * 32 + ec;
      float s0 = red[0][e0] + red[1][e0] + red[2][e0] + red[3][e0] + bias0;
      float s1 = red[0][e0 + 1] + red[1][e0 + 1] + red[2][e0 + 1] + red[3][e0 + 1] + bias1;
      float t0 = fast_tanh(s0), t1 = fast_tanh(s1);
      unsigned short h0b = f2bf_rne(t0);
      unsigned short l0b = f2bf_rne(t0 - bf2f(h0b));
      unsigned short h1b = f2bf_rne(t1);
      unsigned short l1b = f2bf_rne(t1 - bf2f(h1b));
      const size_t off = (size_t)((t + 1) & 1) * BATCH * NH + (size_t)(row0 + er) * NH + h0 + ec;
      __hip_atomic_store((unsigned*)(SH + off), (unsigned)h0b | ((unsigned)h1b << 16),
                         __ATOMIC_RELAXED, __HIP_MEMORY_SCOPE_AGENT);
      __hip_atomic_store((unsigned*)(SL + off), (unsigned)l0b | ((unsigned)l1b << 16),
                         __ATOMIC_RELAXED, __HIP_MEMORY_SCOPE_AGENT);
    }
    __syncthreads();   // per-wave s_waitcnt vmcnt(0) before barrier: stores acked at IC; protects red[]
    if (tid == 0)
      __hip_atomic_store(myflag, (unsigned)(t + 1), __ATOMIC_RELAXED, __HIP_MEMORY_SCOPE_AGENT);
  }
}

__global__ __launch_bounds__(512)
void rnn_readout(const unsigned short* __restrict__ SH,  // final state hi plane (buf0)
                 const unsigned short* __restrict__ SL,  // final state lo plane (buf0)
                 const float* __restrict__ W_ro,          // [128][1024]
                 const float* __restrict__ b_ro,          // [128]
                 float* __restrict__ out)                 // [128][128]
{
  __shared__ float srow[4][NH];
  const int b0 = blockIdx.x * 4;
  for (int i = threadIdx.x; i < 4 * NH; i += 512) {
    const size_t idx = (size_t)(b0 + (i >> 10)) * NH + (i & 1023);
    srow[i >> 10][i & 1023] = bf2f(SH[idx]) + bf2f(SL[idx]);
  }
  __syncthreads();
  const int bb = threadIdx.x >> 7;     // 0..3
  const int o  = threadIdx.x & 127;
  const float* wr = W_ro + (size_t)o * NH;
  float s = 0.f;
  #pragma unroll 4
  for (int k = 0; k < NH; ++k) s += srow[bb][k] * wr[k];
  out[(size_t)(b0 + bb) * NO + o] = s + b_ro[o];
}

extern "C" void kernel_launch(void* const* d_in, const int* in_sizes, int n_in,
                              void* d_out, int out_size, void* d_ws, size_t ws_size,
                              hipStream_t stream) {
  (void)in_sizes; (void)n_in; (void)out_size; (void)ws_size;
  const float* x    = (const float*)d_in[0];
  const float* W_ih = (const float*)d_in[1];
  const float* W_hh = (const float*)d_in[2];
  const float* b_ih = (const float*)d_in[3];
  const float* b_hh = (const float*)d_in[4];
  const float* W_ro = (const float*)d_in[5];
  const float* b_ro = (const float*)d_in[6];
  float* out = (float*)d_out;

  unsigned short* SH = (unsigned short*)d_ws;          // [2][128][1024] bf16 hi (512 KB)
  unsigned short* SL = SH + 2 * BATCH * NH;            // [2][128][1024] bf16 lo (512 KB)
  unsigned* flags = (unsigned*)(SL + 2 * BATCH * NH);  // 8*32*16 u32 (16 KB)

  // state_0 = 0 (buf0 of both planes), flags = 0
  hipMemsetAsync(SH, 0, (size_t)BATCH * NH * sizeof(unsigned short), stream);
  hipMemsetAsync(SL, 0, (size_t)BATCH * NH * sizeof(unsigned short), stream);
  hipMemsetAsync(flags, 0, (size_t)GROUPS * CPG * FSTRIDE * sizeof(unsigned), stream);

  rnn_persistent<<<GROUPS * CPG, 256, 0, stream>>>(x, W_ih, W_hh, b_ih, b_hh, SH, SL, flags);
  // T=512 even -> final state lands in buf0 (= plane base)
  rnn_readout<<<BATCH / 4, 512, 0, stream>>>(SH, SL, W_ro, b_ro, out);
}

// Round 4
// 2850.984 us; speedup vs baseline: 1.0607x; 1.0607x over previous
//
#include <hip/hip_runtime.h>
#include <hip/hip_bf16.h>
#include <stdint.h>

// Persistent-RNN, R4: tag-in-data sync protocol + halved read amplification.
//  - 128 blocks x 512 threads (8 waves). 8 batch-groups x 16 col-blocks.
//  - Block (g,m): batch rows [16g,16g+16), hidden cols [64m,64m+64).
//  - W_hh/W_ih in registers (128+32 VGPR/wave) for all 512 steps.
//  - R3 -> R4:
//      * flags + store-drain + poll-then-load (~3.5 serialized IC round trips)
//        -> TAGGED DATA: state word = (bf16hi<<16)|(bf16lo&~1|parity). Consumer
//        polls its own data words until all tags == (t>>1)&1; the passing poll
//        iteration IS the state load. No flags, no vmcnt drain, 1 barrier/step
//        (red[] double-buffered). ~1-1.5 round trips/step.
//      * 256->128 blocks, 32->16 cols -> 64 cols/block: state read traffic
//        16 MB/step -> 8 MB/step (tests the sc1-bandwidth hypothesis).
//  - WAR safety: observing any fresh word of block B implies B passed its block
//    barrier implies all B's step-(t-1) state reads retired; same-buffer
//    consecutive states have opposite tags so overwritten state never
//    masquerades as the awaited one.

#define TSTEPS 512
#define BATCH  128
#define NI     256
#define NH     1024
#define NO     128
#define NBLK   128
#define NTHR   512
#define NWAVE  8
#define BG     16
#define COLS   64

typedef __attribute__((ext_vector_type(8))) short s16x8;
typedef __attribute__((ext_vector_type(4))) float f32x4;
typedef unsigned long long ull;

__device__ __forceinline__ unsigned short f2bf_rne(float f) {
  unsigned u = __builtin_bit_cast(unsigned, f);
  unsigned r = u + 0x7fffu + ((u >> 16) & 1u);
  return (unsigned short)(r >> 16);
}
__device__ __forceinline__ float bf2f(unsigned short h) {
  unsigned u = ((unsigned)h) << 16;
  return __builtin_bit_cast(float, u);
}
__device__ __forceinline__ void split_bf(float v, short &hi, short &lo) {
  unsigned short h = f2bf_rne(v);
  hi = (short)h;
  lo = (short)f2bf_rne(v - bf2f(h));
}
__device__ __forceinline__ f32x4 mfma16(s16x8 a, s16x8 b, f32x4 c) {
  return __builtin_amdgcn_mfma_f32_16x16x32_bf16(a, b, c, 0, 0, 0);
}
__device__ __forceinline__ float fast_tanh(float a) {
  float cl = fminf(fmaxf(a, -15.f), 15.f);
  float e  = __expf(2.f * cl);
  return (e - 1.f) / (e + 1.f);
}

__global__ __launch_bounds__(NTHR, 2)
void rnn_persistent(const float* __restrict__ x,
                    const float* __restrict__ W_ih,
                    const float* __restrict__ W_hh,
                    const float* __restrict__ b_ih,
                    const float* __restrict__ b_hh,
                    unsigned*    __restrict__ SP)    // [2][128][1024] tagged packed state
{
  const int tid  = threadIdx.x;
  const int wave = tid >> 6;
  const int lane = tid & 63;
  const int lr   = lane & 15;
  const int lq   = lane >> 4;
  const int g    = blockIdx.x >> 4;    // 8 groups
  const int m    = blockIdx.x & 15;    // 16 col-blocks per group
  const int row0 = g * BG;
  const int h0   = m * COLS;
  const int kq0  = wave * 128;         // this wave's hidden-K slice
  const int iq0  = wave * 32;          // this wave's input-K slice

  __shared__ float red[2][NWAVE][1024];

  // ---- persistent W_hh B-fragments: [n-tile 0..3][kb 0..3], hi/lo ----
  // B[k][n] = W_hh[h0+n][k]; lane holds n = lane&15, k = kq0+kb*32+quad*8+j.
  s16x8 whh_hi[4][4], whh_lo[4][4];
  #pragma unroll
  for (int nt = 0; nt < 4; ++nt) {
    const int h = h0 + nt * 16 + lr;
    #pragma unroll
    for (int kb = 0; kb < 4; ++kb) {
      const float* p = W_hh + (size_t)h * NH + kq0 + kb * 32 + lq * 8;
      s16x8 hi, lo;
      #pragma unroll
      for (int j = 0; j < 8; ++j) { short a, b; split_bf(p[j], a, b); hi[j] = a; lo[j] = b; }
      whh_hi[nt][kb] = hi; whh_lo[nt][kb] = lo;
    }
  }
  // ---- persistent W_ih B-fragments: [n-tile 0..3], single 32-wide kb ----
  s16x8 wih_hi[4], wih_lo[4];
  #pragma unroll
  for (int nt = 0; nt < 4; ++nt) {
    const int h = h0 + nt * 16 + lr;
    const float* p = W_ih + (size_t)h * NI + iq0 + lq * 8;
    s16x8 hi, lo;
    #pragma unroll
    for (int j = 0; j < 8; ++j) { short a, b; split_bf(p[j], a, b); hi[j] = a; lo[j] = b; }
    wih_hi[nt] = hi; wih_lo[nt] = lo;
  }

  // epilogue ownership: thread -> row tid>>5, cols 2*(tid&31), +1
  const int er = tid >> 5;
  const int ec = (tid & 31) * 2;
  const float bias0 = b_ih[h0 + ec]     + b_hh[h0 + ec];
  const float bias1 = b_ih[h0 + ec + 1] + b_hh[h0 + ec + 1];

  unsigned* buf0 = SP;
  unsigned* buf1 = SP + BATCH * NH;

  for (int t = 0; t < TSTEPS; ++t) {
    // ---------- x projection first (runs in producers' store-flight shadow) ----------
    f32x4 acc[4];
    #pragma unroll
    for (int nt = 0; nt < 4; ++nt) acc[nt] = (f32x4){0.f, 0.f, 0.f, 0.f};
    {
      const float* xp = x + (size_t)t * BATCH * NI + (size_t)(row0 + lr) * NI + iq0 + lq * 8;
      s16x8 xhi, xlo;
      #pragma unroll
      for (int j = 0; j < 8; ++j) { short a, b; split_bf(xp[j], a, b); xhi[j] = a; xlo[j] = b; }
      #pragma unroll
      for (int nt = 0; nt < 4; ++nt) {
        acc[nt] = mfma16(xhi, wih_hi[nt], acc[nt]);
        acc[nt] = mfma16(xhi, wih_lo[nt], acc[nt]);
        acc[nt] = mfma16(xlo, wih_hi[nt], acc[nt]);
      }
    }
    // ---------- poll own state words until tags match; passing pass IS the load ----------
    const unsigned etag = (unsigned)((t >> 1) & 1);
    const ull* sb = (const ull*)((t & 1 ? buf1 : buf0)
                                 + (size_t)(row0 + lr) * NH + kq0 + lq * 8);
    ull sv[16];
    for (;;) {
      #pragma unroll
      for (int kb = 0; kb < 4; ++kb)
        #pragma unroll
        for (int i = 0; i < 4; ++i)
          sv[kb * 4 + i] = __hip_atomic_load(sb + kb * 16 + i,
                                             __ATOMIC_RELAXED, __HIP_MEMORY_SCOPE_AGENT);
      unsigned bad = 0;
      #pragma unroll
      for (int i = 0; i < 16; ++i)
        bad |= ((unsigned)sv[i] ^ etag) | ((unsigned)(sv[i] >> 32) ^ etag);
      if ((bad & 1u) == 0) break;
    }
    // ---------- recurrent MFMAs (unpack + 3-product bf16x2) ----------
    #pragma unroll
    for (int kb = 0; kb < 4; ++kb) {
      s16x8 shi, slo;
      #pragma unroll
      for (int p = 0; p < 4; ++p) {
        ull v = sv[kb * 4 + p];
        unsigned a = (unsigned)v, b = (unsigned)(v >> 32);
        shi[p * 2]     = (short)(a >> 16); slo[p * 2]     = (short)(a & 0xffffu);
        shi[p * 2 + 1] = (short)(b >> 16); slo[p * 2 + 1] = (short)(b & 0xffffu);
      }
      #pragma unroll
      for (int nt = 0; nt < 4; ++nt) {
        acc[nt] = mfma16(shi, whh_hi[nt][kb], acc[nt]);
        acc[nt] = mfma16(shi, whh_lo[nt][kb], acc[nt]);
        acc[nt] = mfma16(slo, whh_hi[nt][kb], acc[nt]);
      }
    }
    // ---------- cross-wave K reduction (double-buffered -> ONE barrier/step) ----------
    // C/D layout: col = lane&15, row = quad*4 + reg (m89/m91 verified)
    const int rbi = t & 1;
    #pragma unroll
    for (int nt = 0; nt < 4; ++nt)
      #pragma unroll
      for (int r = 0; r < 4; ++r)
        red[rbi][wave][(lq * 4 + r) * 64 + nt * 16 + lr] = acc[nt][r];
    __syncthreads();
    // ---------- epilogue: reduce 8 waves, tanh, tagged store (fire, no drain) ----------
    {
      float s0 = bias0, s1 = bias1;
      #pragma unroll
      for (int w = 0; w < NWAVE; ++w) {
        float2 v = *(const float2*)&red[rbi][w][er * 64 + ec];
        s0 += v.x; s1 += v.y;
      }
      float t0 = fast_tanh(s0), t1 = fast_tanh(s1);
      const unsigned otag = (unsigned)(((t + 1) >> 1) & 1);
      unsigned short h0b = f2bf_rne(t0);
      unsigned       l0b = ((f2bf_rne(t0 - bf2f(h0b)) & 0xfffeu) | otag);
      unsigned short h1b = f2bf_rne(t1);
      unsigned       l1b = ((f2bf_rne(t1 - bf2f(h1b)) & 0xfffeu) | otag);
      ull pk = ((ull)(((unsigned)h1b << 16) | l1b) << 32)
             |  (ull)(((unsigned)h0b << 16) | l0b);
      ull* op = (ull*)(((t + 1) & 1 ? buf1 : buf0) + (size_t)(row0 + er) * NH + h0 + ec);
      __hip_atomic_store(op, pk, __ATOMIC_RELAXED, __HIP_MEMORY_SCOPE_AGENT);
    }
  }
}

__global__ __launch_bounds__(256)
void init_buf1(unsigned* __restrict__ SP) {
  // buffer1 stale-tag init: consumers of s=1 expect tag 0 -> mark stale with LSB=1
  const int i = blockIdx.x * 256 + threadIdx.x;
  SP[BATCH * NH + i] = 1u;
}

__global__ __launch_bounds__(512)
void rnn_readout(const unsigned* __restrict__ SP,      // final state = buf0 (T even)
                 const float* __restrict__ W_ro,       // [128][1024]
                 const float* __restrict__ b_ro,       // [128]
                 float* __restrict__ out)              // [128][128]
{
  __shared__ float srow[4][NH];
  const int b0 = blockIdx.x * 4;
  for (int i = threadIdx.x; i < 4 * NH; i += 512) {
    unsigned u = SP[(size_t)(b0 + (i >> 10)) * NH + (i & 1023)];
    srow[i >> 10][i & 1023] = bf2f((unsigned short)(u >> 16)) + bf2f((unsigned short)(u & 0xffffu));
  }
  __syncthreads();
  const int bb = threadIdx.x >> 7;
  const int o  = threadIdx.x & 127;
  const float* wr = W_ro + (size_t)o * NH;
  float s = 0.f;
  #pragma unroll 4
  for (int k = 0; k < NH; ++k) s += srow[bb][k] * wr[k];
  out[(size_t)(b0 + bb) * NO + o] = s + b_ro[o];
}

extern "C" void kernel_launch(void* const* d_in, const int* in_sizes, int n_in,
                              void* d_out, int out_size, void* d_ws, size_t ws_size,
                              hipStream_t stream) {
  (void)in_sizes; (void)n_in; (void)out_size; (void)ws_size;
  const float* x    = (const float*)d_in[0];
  const float* W_ih = (const float*)d_in[1];
  const float* W_hh = (const float*)d_in[2];
  const float* b_ih = (const float*)d_in[3];
  const float* b_hh = (const float*)d_in[4];
  const float* W_ro = (const float*)d_in[5];
  const float* b_ro = (const float*)d_in[6];
  float* out = (float*)d_out;

  unsigned* SP = (unsigned*)d_ws;   // [2][128][1024] u32 = 1 MB

  // buf0 = state s=0: zeros, tag LSB=0 (expected tag for s=0 is 0) -> plain memset
  hipMemsetAsync(SP, 0, (size_t)BATCH * NH * sizeof(unsigned), stream);
  // buf1 = stale marker (tag 1 != expected 0 for s=1)
  init_buf1<<<(BATCH * NH) / 256, 256, 0, stream>>>(SP);

  rnn_persistent<<<NBLK, NTHR, 0, stream>>>(x, W_ih, W_hh, b_ih, b_hh, SP);
  // T=512 even -> final state in buf0
  rnn_readout<<<BATCH / 4, 512, 0, stream>>>(SP, W_ro, b_ro, out);
}